// Round 7
// baseline (1176.965 us; speedup 1.0000x reference)
//
#include <hip/hip_runtime.h>
#include <hip/hip_bf16.h>

#define IN_DIM 2048
#define HID    1024
#define ATT    40
#define BATCH  4096

// GEMM: 256x256 tile, BK=64, 8 waves (2M x 4N), 4-slot LDS ring per matrix
#define GBM 256
#define GBN 256
#define GBK 64
#define NT  (IN_DIM / GBK)   // 32 K-tiles

typedef unsigned short u16;
typedef __attribute__((ext_vector_type(8))) __bf16 bf16x8;
typedef __attribute__((ext_vector_type(4))) float  f32x4;

struct alignas(8)  u16x4 { u16 a, b, c, d; };
struct alignas(16) u16x8 { u16x4 lo, hi; };

#define FENCE() asm volatile("" ::: "memory")
#define BAR()   do { FENCE(); __builtin_amdgcn_s_barrier(); FENCE(); } while (0)

__device__ __forceinline__ u16 f2bf(float f) {
    unsigned int u = __float_as_uint(f);
    unsigned int r = (u + 0x7fffu + ((u >> 16) & 1u)) >> 16;   // RNE
    return (u16)r;
}
__device__ __forceinline__ float f4get(const float4& v, int j) {
    return reinterpret_cast<const float*>(&v)[j];
}

// async global->LDS 16B/lane; LDS dest is wave-uniform base + lane*16
__device__ __forceinline__ void load16_to_lds(const void* g, void* l) {
    __builtin_amdgcn_global_load_lds(
        (const __attribute__((address_space(1))) unsigned int*)(uintptr_t)g,
        (__attribute__((address_space(3))) unsigned int*)(uintptr_t)l,
        16, 0, 0);
}

// ---------------- x fp32 -> bf16 (same layout) ----------------
__global__ void convert_x(const float* __restrict__ x, u16* __restrict__ xb) {
    int i = (blockIdx.x * 256 + threadIdx.x) * 4;
    float4 v = *(const float4*)(x + i);
    u16x4 o = { f2bf(v.x), f2bf(v.y), f2bf(v.z), f2bf(v.w) };
    *(u16x4*)(xb + i) = o;
}

// ---------------- W1 (a,d,h) fp32 -> (a,h,d) bf16 ----------------
// 128(d) x 128(h) tile per block, 256 threads.
__global__ __launch_bounds__(256) void transpose_w1(const float* __restrict__ W1,
                                                    u16* __restrict__ W1t) {
    __shared__ __align__(16) u16 tile[128 * 136];   // pad 8 u16 (16B) per row
    const int a  = blockIdx.z;
    const int d0 = blockIdx.y * 128;
    const int h0 = blockIdx.x * 128;
    const float* src = W1 + (size_t)a * IN_DIM * HID + (size_t)d0 * HID + h0;
    u16* dst = W1t + (size_t)a * HID * IN_DIM + (size_t)h0 * IN_DIM + d0;

    const int rg = threadIdx.x >> 5;   // 0..7  -> d row-group (4 rows) within pp
    const int cg = threadIdx.x & 31;   // 0..31 -> h chunk of 4

    float4 v[4][4];
    #pragma unroll
    for (int pp = 0; pp < 4; ++pp) {
        int r0 = pp * 32 + rg * 4;
        #pragma unroll
        for (int q = 0; q < 4; ++q)
            v[pp][q] = *(const float4*)(src + (size_t)(r0 + q) * HID + cg * 4);
    }
    #pragma unroll
    for (int pp = 0; pp < 4; ++pp) {
        int r0 = pp * 32 + rg * 4;
        #pragma unroll
        for (int j = 0; j < 4; ++j) {
            int h = cg * 4 + j;
            u16x4 o = { f2bf(f4get(v[pp][0], j)), f2bf(f4get(v[pp][1], j)),
                        f2bf(f4get(v[pp][2], j)), f2bf(f4get(v[pp][3], j)) };
            *(u16x4*)&tile[h * 136 + r0] = o;
        }
    }
    __syncthreads();
    const int hg = threadIdx.x >> 4;   // 0..15
    const int dc = threadIdx.x & 15;   // 16B chunk of d (8 u16)
    #pragma unroll
    for (int qq = 0; qq < 8; ++qq) {
        int h = qq * 16 + hg;
        u16x8 o = *(const u16x8*)&tile[h * 136 + dc * 8];
        *(u16x8*)(dst + (size_t)h * IN_DIM + dc * 8) = o;
    }
}

// ---------------- fused GEMM + bias + gelu + W2-dot (atomic partials) -----------
// 256x256x64 phase-split schedule, 8 waves, 128KB LDS (4 half-tile ring slots
// per matrix), counted vmcnt (never 0 in steady state), raw s_barrier, setprio.
//
// Half-tile = 128 rows x 64 k (16KB). Slot of half h of K-tile t = (2t+h)&3.
// Stage schedule per tile t: ph0: A0(t+1), ph1: A1(t+1), ph3: B0(t+2)+B1(t+2).
// Waits: vmcnt(4) at end of ph3; tail vmcnt(0) at t=NT-2.
__global__ __launch_bounds__(512, 2) void gemm_fused(
    const u16* __restrict__ xb,    // [4096][2048] bf16
    const u16* __restrict__ w1t,   // [40][1024][2048] bf16 (B^T: n-major, k-contig)
    const float* __restrict__ b1,  // [40][1024]
    const float* __restrict__ w2,  // [40][1024]
    float* __restrict__ partial)   // [4096][40], pre-zeroed
{
    __shared__ __align__(16) u16 smem[65536];   // A: [0,32768) B: [32768,65536)

    // bijective XCD-chunked swizzle (2560 blocks, 2560 % 8 == 0)
    const int fid = blockIdx.x + 16 * (blockIdx.y + 4 * blockIdx.z);
    const int nf  = (fid & 7) * (2560 >> 3) + (fid >> 3);
    const int a   = nf >> 6;           // 64 blocks per head
    const int rr  = nf & 63;
    const int m0  = (rr & 15) * GBM;   // m fastest within chunk -> B-panel L2 reuse
    const int n0  = (rr >> 4) * GBN;

    const int tid   = threadIdx.x;
    const int w     = tid >> 6;
    const int l     = tid & 63;
    const int quad  = l >> 4;
    const int lr    = l & 15;
    const int mh    = w >> 2;          // wave's A half-tile (0/1)
    const int nh    = (w >> 1) & 1;    // wave's B half-tile (0/1)
    const int wm    = mh * 128;
    const int wn    = (w & 3) * 64;
    const int nrow0 = (w & 1) * 64;    // row offset within B half

    // staging offsets (global elements); same XOR pre-swizzle as read side
    int offS[2];
    #pragma unroll
    for (int j = 0; j < 2; ++j) {
        int p   = j * 512 + tid;
        int row = p >> 3;              // 0..127 within half-tile
        int kc  = (p & 7) ^ (row & 7);
        offS[j] = row * IN_DIM + kc * 8;
    }
    const u16* Ab = xb + (size_t)m0 * IN_DIM;
    const u16* Bb = w1t + (size_t)a * ((size_t)HID * IN_DIM) + (size_t)n0 * IN_DIM;

    auto stageA = [&](int t, int h) {
        const u16* g = Ab + (size_t)h * 128 * IN_DIM + t * GBK;
        int sb = (((2 * t + h) & 3) << 13) + (w << 9);   // slot*8192 + w*512 u16
        load16_to_lds(g + offS[0], &smem[sb]);
        load16_to_lds(g + offS[1], &smem[sb + 4096]);
    };
    auto stageB = [&](int t, int h) {
        const u16* g = Bb + (size_t)h * 128 * IN_DIM + t * GBK;
        int sb = 32768 + (((2 * t + h) & 3) << 13) + (w << 9);
        load16_to_lds(g + offS[0], &smem[sb]);
        load16_to_lds(g + offS[1], &smem[sb + 4096]);
    };

    f32x4 acc[8][4];
    #pragma unroll
    for (int i = 0; i < 8; ++i)
        #pragma unroll
        for (int j = 0; j < 4; ++j)
            acc[i][j] = (f32x4){0.f, 0.f, 0.f, 0.f};

    // prologue: issue order must match steady-state relative order
    stageB(0, 0); stageB(0, 1); stageA(0, 0); stageA(0, 1); stageB(1, 0); stageB(1, 1);
    asm volatile("s_waitcnt vmcnt(4)" ::: "memory");   // tile 0's 4 halves landed
    BAR();

    for (int t = 0; t < NT; ++t) {
        const int abase = (((2 * t + mh) & 3) << 13);
        const int bbase = 32768 + (((2 * t + nh) & 3) << 13);
        bf16x8 af[4], bf[4];

        // ---------- ph0: ks=0, mq=0 ----------
        #pragma unroll
        for (int f = 0; f < 4; ++f) {
            int rb = nrow0 + f * 16 + lr;
            bf[f] = *(const bf16x8*)&smem[bbase + rb * 64 + (quad ^ (rb & 7)) * 8];
        }
        #pragma unroll
        for (int f = 0; f < 4; ++f) {
            int ra = f * 16 + lr;
            af[f] = *(const bf16x8*)&smem[abase + ra * 64 + (quad ^ (ra & 7)) * 8];
        }
        if (t + 1 < NT) stageA(t + 1, 0);
        BAR();
        __builtin_amdgcn_s_setprio(1);
        #pragma unroll
        for (int fm = 0; fm < 4; ++fm)
            #pragma unroll
            for (int fn = 0; fn < 4; ++fn)
                acc[fm][fn] = __builtin_amdgcn_mfma_f32_16x16x32_bf16(
                    af[fm], bf[fn], acc[fm][fn], 0, 0, 0);
        __builtin_amdgcn_s_setprio(0);
        BAR();

        // ---------- ph1: ks=0, mq=1 (reuse bf) ----------
        #pragma unroll
        for (int f = 0; f < 4; ++f) {
            int ra = 64 + f * 16 + lr;
            af[f] = *(const bf16x8*)&smem[abase + ra * 64 + (quad ^ (ra & 7)) * 8];
        }
        if (t + 1 < NT) stageA(t + 1, 1);
        BAR();
        __builtin_amdgcn_s_setprio(1);
        #pragma unroll
        for (int fm = 0; fm < 4; ++fm)
            #pragma unroll
            for (int fn = 0; fn < 4; ++fn)
                acc[4 + fm][fn] = __builtin_amdgcn_mfma_f32_16x16x32_bf16(
                    af[fm], bf[fn], acc[4 + fm][fn], 0, 0, 0);
        __builtin_amdgcn_s_setprio(0);
        BAR();

        // ---------- ph2: ks=1, mq=0 ----------
        #pragma unroll
        for (int f = 0; f < 4; ++f) {
            int rb = nrow0 + f * 16 + lr;
            bf[f] = *(const bf16x8*)&smem[bbase + rb * 64 + ((4 + quad) ^ (rb & 7)) * 8];
        }
        #pragma unroll
        for (int f = 0; f < 4; ++f) {
            int ra = f * 16 + lr;
            af[f] = *(const bf16x8*)&smem[abase + ra * 64 + ((4 + quad) ^ (ra & 7)) * 8];
        }
        BAR();
        __builtin_amdgcn_s_setprio(1);
        #pragma unroll
        for (int fm = 0; fm < 4; ++fm)
            #pragma unroll
            for (int fn = 0; fn < 4; ++fn)
                acc[fm][fn] = __builtin_amdgcn_mfma_f32_16x16x32_bf16(
                    af[fm], bf[fn], acc[fm][fn], 0, 0, 0);
        __builtin_amdgcn_s_setprio(0);
        BAR();

        // ---------- ph3: ks=1, mq=1 (reuse bf) ----------
        #pragma unroll
        for (int f = 0; f < 4; ++f) {
            int ra = 64 + f * 16 + lr;
            af[f] = *(const bf16x8*)&smem[abase + ra * 64 + ((4 + quad) ^ (ra & 7)) * 8];
        }
        if (t + 2 < NT) { stageB(t + 2, 0); stageB(t + 2, 1); }
        BAR();
        __builtin_amdgcn_s_setprio(1);
        #pragma unroll
        for (int fm = 0; fm < 4; ++fm)
            #pragma unroll
            for (int fn = 0; fn < 4; ++fn)
                acc[4 + fm][fn] = __builtin_amdgcn_mfma_f32_16x16x32_bf16(
                    af[fm], bf[fn], acc[4 + fm][fn], 0, 0, 0);
        __builtin_amdgcn_s_setprio(0);
        // counted wait for NEXT tile's halves (before the barrier ph0 reads behind)
        if (t < NT - 2)       { asm volatile("s_waitcnt vmcnt(4)" ::: "memory"); }
        else if (t == NT - 2) { asm volatile("s_waitcnt vmcnt(0)" ::: "memory"); }
        BAR();
    }

    // ---- epilogue: +b1, exact gelu, *W2, reduce over this wave's 64 cols ----
    float b1v[4], w2v[4];
    #pragma unroll
    for (int fn = 0; fn < 4; ++fn) {
        int col = n0 + wn + fn * 16 + lr;
        b1v[fn] = b1[a * HID + col];
        w2v[fn] = w2[a * HID + col];
    }
    #pragma unroll
    for (int fm = 0; fm < 8; ++fm) {
        #pragma unroll
        for (int r = 0; r < 4; ++r) {
            float s = 0.f;
            #pragma unroll
            for (int fn = 0; fn < 4; ++fn) {
                float z = acc[fm][fn][r] + b1v[fn];
                float g = 0.5f * z * (1.0f + erff(z * 0.70710678118654752f));
                s += g * w2v[fn];
            }
            s += __shfl_xor(s, 1, 64);
            s += __shfl_xor(s, 2, 64);
            s += __shfl_xor(s, 4, 64);
            s += __shfl_xor(s, 8, 64);
            if (lr == 0) {
                int grow = m0 + wm + fm * 16 + quad * 4 + r;
                atomicAdd(&partial[grow * ATT + a], s);
            }
        }
    }
}

// ---------------- sigmoid(partial + b2) -> out ----------------
__global__ void finish_kernel(const float* __restrict__ partial,
                              const float* __restrict__ b2,
                              float* __restrict__ out, int n) {
    int i = blockIdx.x * 256 + threadIdx.x;
    if (i < n) {
        float z = partial[i] + b2[i % ATT];
        out[i] = 1.0f / (1.0f + expf(-z));
    }
}

extern "C" void kernel_launch(void* const* d_in, const int* in_sizes, int n_in,
                              void* d_out, int out_size, void* d_ws, size_t ws_size,
                              hipStream_t stream) {
    const float* x  = (const float*)d_in[0];
    const float* W1 = (const float*)d_in[1];
    const float* b1 = (const float*)d_in[2];
    const float* W2 = (const float*)d_in[3];
    const float* b2 = (const float*)d_in[4];
    float* out = (float*)d_out;

    char* ws = (char*)d_ws;
    float* partial = (float*)ws;                                   // 640 KB
    u16*   xb      = (u16*)(ws + 655360);                          // 16 MB
    u16*   w1t     = (u16*)(ws + 655360 + 16777216);               // 160 MB

    hipMemsetAsync(partial, 0, (size_t)BATCH * ATT * sizeof(float), stream);
    convert_x<<<dim3(BATCH * IN_DIM / (256 * 4)), dim3(256), 0, stream>>>(x, xb);
    transpose_w1<<<dim3(HID / 128, IN_DIM / 128, ATT), dim3(256), 0, stream>>>(W1, w1t);
    gemm_fused<<<dim3(BATCH / GBM, HID / GBN, ATT), dim3(512), 0, stream>>>(
        xb, w1t, b1, W2, partial);
    finish_kernel<<<dim3((BATCH * ATT + 255) / 256), dim3(256), 0, stream>>>(
        partial, b2, out, BATCH * ATT);
}

// Round 8
// 1128.584 us; speedup vs baseline: 1.0429x; 1.0429x over previous
//
#include <hip/hip_runtime.h>
#include <hip/hip_bf16.h>

#define IN_DIM 2048
#define HID    1024
#define ATT    40
#define BATCH  4096

#define BM 128
#define BN 128
#define BK 64

typedef unsigned short u16;
typedef __attribute__((ext_vector_type(8))) __bf16 bf16x8;
typedef __attribute__((ext_vector_type(4))) float  f32x4;

struct alignas(8)  u16x4 { u16 a, b, c, d; };
struct alignas(16) u16x8 { u16x4 lo, hi; };

__device__ __forceinline__ u16 f2bf(float f) {
    unsigned int u = __float_as_uint(f);
    unsigned int r = (u + 0x7fffu + ((u >> 16) & 1u)) >> 16;   // RNE
    return (u16)r;
}
__device__ __forceinline__ float f4get(const float4& v, int j) {
    return reinterpret_cast<const float*>(&v)[j];
}

// async global->LDS 16B/lane; LDS dest is wave-uniform base + lane*16
__device__ __forceinline__ void load16_to_lds(const void* g, void* l) {
    __builtin_amdgcn_global_load_lds(
        (const __attribute__((address_space(1))) unsigned int*)(uintptr_t)g,
        (__attribute__((address_space(3))) unsigned int*)(uintptr_t)l,
        16, 0, 0);
}

// ---------------- x fp32 -> bf16 (same layout) ----------------
__global__ void convert_x(const float* __restrict__ x, u16* __restrict__ xb) {
    int i = (blockIdx.x * 256 + threadIdx.x) * 4;
    float4 v = *(const float4*)(x + i);
    u16x4 o = { f2bf(v.x), f2bf(v.y), f2bf(v.z), f2bf(v.w) };
    *(u16x4*)(xb + i) = o;
}

// ---------------- W1 (a,d,h) fp32 -> (a,h,d) bf16 ----------------
// 128(d) x 128(h) tile, 256 threads. Phase-1 LDS writes XOR-swizzled:
// 8B d-chunk c stored at c ^ (((h>>2)&7)<<1) -> 16-way conflict (old +8 pad
// layout: dlane=4 rows x 272B => banks {b,b+16}) reduced to the 4-way floor.
// Even XOR preserves 16B chunk-pairs so phase-2 reads stay u16x8.
__global__ __launch_bounds__(256) void transpose_w1(const float* __restrict__ W1,
                                                    u16* __restrict__ W1t) {
    __shared__ __align__(16) u16 tile[128 * 128];
    const int a  = blockIdx.z;
    const int d0 = blockIdx.y * 128;
    const int h0 = blockIdx.x * 128;
    const float* src = W1 + (size_t)a * IN_DIM * HID + (size_t)d0 * HID + h0;
    u16* dst = W1t + (size_t)a * HID * IN_DIM + (size_t)h0 * IN_DIM + d0;

    const int rg = threadIdx.x >> 5;   // 0..7  -> d sub-group
    const int cg = threadIdx.x & 31;   // 0..31 -> h group (h = 4cg..4cg+3)

    // ---- phase 1: 16 outstanding float4 loads (512B read segments) ----
    float4 v[4][4];
    #pragma unroll
    for (int pp = 0; pp < 4; ++pp) {
        int r0 = pp * 32 + rg * 4;
        #pragma unroll
        for (int q = 0; q < 4; ++q)
            v[pp][q] = *(const float4*)(src + (size_t)(r0 + q) * HID + cg * 4);
    }
    // ---- convert + 4x4 in-register transpose -> swizzled LDS [h][d] ----
    const int s1 = (cg & 7) << 1;      // h>>2 == cg for this thread's 4 h-rows
    #pragma unroll
    for (int pp = 0; pp < 4; ++pp) {
        #pragma unroll
        for (int j = 0; j < 4; ++j) {
            int h = cg * 4 + j;
            int c = pp * 8 + rg;       // 8B d-chunk index 0..31
            u16x4 o = { f2bf(f4get(v[pp][0], j)), f2bf(f4get(v[pp][1], j)),
                        f2bf(f4get(v[pp][2], j)), f2bf(f4get(v[pp][3], j)) };
            *(u16x4*)&tile[h * 128 + (c ^ s1) * 4] = o;
        }
    }
    __syncthreads();
    // ---- phase 2: 16B swizzled LDS reads, 256B coalesced global stores ----
    const int hg = threadIdx.x >> 4;   // 0..15
    const int dc = threadIdx.x & 15;   // 16B chunk of d
    #pragma unroll
    for (int qq = 0; qq < 8; ++qq) {
        int h  = qq * 16 + hg;
        int s2 = ((h >> 2) & 7) << 1;
        u16x8 o = *(const u16x8*)&tile[h * 128 + ((2 * dc) ^ s2) * 4];
        *(u16x8*)(dst + (size_t)h * IN_DIM + dc * 8) = o;
    }
}

// ---------------- fused GEMM + bias + gelu + W2-dot (atomic partials) ----------------
// Reverted to the measured 700us 128x128 structure; single tweak vs that
// baseline: launch_bounds min-waves 3 -> 4 (VGPR 60+64acc=124 <= 128, LDS
// 32KB -> 5 blocks) to raise residency from ~3 to 4 blocks/CU.
__global__ __launch_bounds__(256, 4) void gemm_fused(
    const u16* __restrict__ xb,    // [4096][2048] bf16
    const u16* __restrict__ w1t,   // [40][1024][2048] bf16 (B^T: n-major, k-contig)
    const float* __restrict__ b1,  // [40][1024]
    const float* __restrict__ w2,  // [40][1024]
    float* __restrict__ partial)   // [4096][40], pre-zeroed
{
    __shared__ __align__(16) u16 smem[2 * BM * BK];   // A:[0,8192) B:[8192,16384) u16
    const int a  = blockIdx.z;
    const int m0 = blockIdx.x * BM;
    const int n0 = blockIdx.y * BN;

    const int tid  = threadIdx.x;
    const int w    = tid >> 6;
    const int l    = tid & 63;
    const int quad = l >> 4;
    const int lr   = l & 15;
    const int wm   = (w >> 1) * 64;
    const int wn   = (w & 1) * 64;

    // ---- loop-invariant staging offsets (elements) ----
    int offG[4];
    #pragma unroll
    for (int j = 0; j < 4; ++j) {
        int p   = j * 256 + tid;
        int row = p >> 3;
        int kc  = (p & 7) ^ (row & 7);
        offG[j] = row * IN_DIM + kc * 8;
    }
    // ---- loop-invariant LDS read offsets (u16 elements) ----
    int offLA[2][4], offLB[2][4];
    #pragma unroll
    for (int ks = 0; ks < 2; ++ks)
        #pragma unroll
        for (int f = 0; f < 4; ++f) {
            int rowA = wm + f * 16 + lr;
            int kcA  = (ks * 4 + quad) ^ (rowA & 7);
            offLA[ks][f] = rowA * BK + kcA * 8;
            int rowB = wn + f * 16 + lr;
            int kcB  = (ks * 4 + quad) ^ (rowB & 7);
            offLB[ks][f] = BM * BK + rowB * BK + kcB * 8;
        }

    const u16* Abase = xb + (size_t)m0 * IN_DIM;
    const u16* Bbase = w1t + (size_t)a * ((size_t)HID * IN_DIM) + (size_t)n0 * IN_DIM;

    f32x4 acc[4][4];
    #pragma unroll
    for (int i = 0; i < 4; ++i)
        #pragma unroll
        for (int j = 0; j < 4; ++j)
            acc[i][j] = (f32x4){0.f, 0.f, 0.f, 0.f};

    for (int k0 = 0; k0 < IN_DIM; k0 += BK) {
        const u16* Ak = Abase + k0;   // uniform: one scalar add/iter
        const u16* Bk = Bbase + k0;
        #pragma unroll
        for (int j = 0; j < 4; ++j)
            load16_to_lds(Ak + offG[j], &smem[(j * 256 + w * 64) * 8]);
        #pragma unroll
        for (int j = 0; j < 4; ++j)
            load16_to_lds(Bk + offG[j], &smem[BM * BK + (j * 256 + w * 64) * 8]);
        __syncthreads();

        #pragma unroll
        for (int ks = 0; ks < 2; ++ks) {
            bf16x8 af[4], bfr[4];
            #pragma unroll
            for (int f = 0; f < 4; ++f) af[f]  = *(const bf16x8*)&smem[offLA[ks][f]];
            #pragma unroll
            for (int f = 0; f < 4; ++f) bfr[f] = *(const bf16x8*)&smem[offLB[ks][f]];
            #pragma unroll
            for (int fm = 0; fm < 4; ++fm)
                #pragma unroll
                for (int fn = 0; fn < 4; ++fn)
                    acc[fm][fn] = __builtin_amdgcn_mfma_f32_16x16x32_bf16(
                        af[fm], bfr[fn], acc[fm][fn], 0, 0, 0);
        }
        __syncthreads();
    }

    // ---- epilogue: +b1, exact gelu, *W2, reduce over this tile's 128 cols ----
    float b1v[4], w2v[4];
    #pragma unroll
    for (int fn = 0; fn < 4; ++fn) {
        int col = n0 + wn + fn * 16 + lr;
        b1v[fn] = b1[a * HID + col];
        w2v[fn] = w2[a * HID + col];
    }
    #pragma unroll
    for (int fm = 0; fm < 4; ++fm) {
        #pragma unroll
        for (int r = 0; r < 4; ++r) {
            float s = 0.f;
            #pragma unroll
            for (int fn = 0; fn < 4; ++fn) {
                float z = acc[fm][fn][r] + b1v[fn];
                float g = 0.5f * z * (1.0f + erff(z * 0.70710678118654752f));
                s += g * w2v[fn];
            }
            s += __shfl_xor(s, 1, 64);
            s += __shfl_xor(s, 2, 64);
            s += __shfl_xor(s, 4, 64);
            s += __shfl_xor(s, 8, 64);
            if (lr == 0) {
                int grow = m0 + wm + fm * 16 + quad * 4 + r;
                atomicAdd(&partial[grow * ATT + a], s);
            }
        }
    }
}

// ---------------- sigmoid(partial + b2) -> out ----------------
__global__ void finish_kernel(const float* __restrict__ partial,
                              const float* __restrict__ b2,
                              float* __restrict__ out, int n) {
    int i = blockIdx.x * 256 + threadIdx.x;
    if (i < n) {
        float z = partial[i] + b2[i % ATT];
        out[i] = 1.0f / (1.0f + expf(-z));
    }
}

extern "C" void kernel_launch(void* const* d_in, const int* in_sizes, int n_in,
                              void* d_out, int out_size, void* d_ws, size_t ws_size,
                              hipStream_t stream) {
    const float* x  = (const float*)d_in[0];
    const float* W1 = (const float*)d_in[1];
    const float* b1 = (const float*)d_in[2];
    const float* W2 = (const float*)d_in[3];
    const float* b2 = (const float*)d_in[4];
    float* out = (float*)d_out;

    char* ws = (char*)d_ws;
    float* partial = (float*)ws;                                   // 640 KB
    u16*   xb      = (u16*)(ws + 655360);                          // 16 MB
    u16*   w1t     = (u16*)(ws + 655360 + 16777216);               // 160 MB

    hipMemsetAsync(partial, 0, (size_t)BATCH * ATT * sizeof(float), stream);
    convert_x<<<dim3(BATCH * IN_DIM / (256 * 4)), dim3(256), 0, stream>>>(x, xb);
    transpose_w1<<<dim3(HID / 128, IN_DIM / 128, ATT), dim3(256), 0, stream>>>(W1, w1t);
    gemm_fused<<<dim3(BATCH / BM, HID / BN, ATT), dim3(256), 0, stream>>>(
        xb, w1t, b1, W2, partial);
    finish_kernel<<<dim3((BATCH * ATT + 255) / 256), dim3(256), 0, stream>>>(
        partial, b2, out, BATCH * ATT);
}